// Round 5
// baseline (73.053 us; speedup 1.0000x reference)
//
#include <hip/hip_runtime.h>

// DeepPoly ReLU — HBM-bound streaming, 402.6 MB single-touch traffic.
// Round 5: keep the 2-kernel split (stream-count win from R4). Kernel B now
// issues per-array LOAD BURSTS (8x16B contiguous per block per array) instead
// of interleaving lo/up per index — better DRAM page/channel locality.
// Stores likewise bursted per array. Nontemporal throughout (no reuse).

#define U 8  // float4 per thread per tile

typedef float f32x4 __attribute__((ext_vector_type(4)));

__device__ __forceinline__ f32x4 nt_load(const f32x4* p) {
    return __builtin_nontemporal_load(p);
}
__device__ __forceinline__ void nt_store(f32x4* p, f32x4 v) {
    __builtin_nontemporal_store(v, p);
}

__device__ __forceinline__ void bounds_one(float lf, float uf,
                                           float& lo_o, float& up_o) {
    const bool neg = (uf <= 0.0f);          // fully inactive
    const bool pos = (lf >= 0.0f);          // fully active (after neg)
    const bool crossing = (!neg) && (!pos);
    const float denom = crossing ? (uf - lf) : 1.0f;  // >0 when crossing
    const float su = (uf / denom) * uf;     // slope*u, uniform (no divergence)
    lo_o = neg ? 0.0f : (pos ? uf : lf);
    up_o = neg ? 0.0f : (pos ? uf : su);
}

// ---- Kernel A: relu copy (1R + 1W) ----
__global__ void __launch_bounds__(256) relu_x_kernel(
    const f32x4* __restrict__ x, f32x4* __restrict__ x_out, int n4)
{
    const int tile = blockDim.x * U;             // 2048 float4 = 32 KiB
    const int ntiles = n4 / tile;
    for (int t = blockIdx.x; t < ntiles; t += gridDim.x) {
        const long long base = (long long)t * tile + threadIdx.x;
        f32x4 v[U];
        #pragma unroll
        for (int k = 0; k < U; ++k) v[k] = nt_load(&x[base + k * blockDim.x]);
        #pragma unroll
        for (int k = 0; k < U; ++k) {
            f32x4 r;
            r.x = fmaxf(v[k].x, 0.0f); r.y = fmaxf(v[k].y, 0.0f);
            r.z = fmaxf(v[k].z, 0.0f); r.w = fmaxf(v[k].w, 0.0f);
            nt_store(&x_out[base + k * blockDim.x], r);
        }
    }
    const int rem = ntiles * tile;
    for (int i = rem + blockIdx.x * blockDim.x + threadIdx.x; i < n4;
         i += gridDim.x * blockDim.x) {
        f32x4 v = nt_load(&x[i]);
        f32x4 r;
        r.x = fmaxf(v.x, 0.0f); r.y = fmaxf(v.y, 0.0f);
        r.z = fmaxf(v.z, 0.0f); r.w = fmaxf(v.w, 0.0f);
        nt_store(&x_out[i], r);
    }
}

// ---- Kernel B: bounds (2R + 2W), per-array bursts ----
__global__ void __launch_bounds__(256) relu_bounds_kernel(
    const f32x4* __restrict__ lo, const f32x4* __restrict__ up,
    f32x4* __restrict__ lo_out, f32x4* __restrict__ up_out, int n4)
{
    const int tile = blockDim.x * U;
    const int ntiles = n4 / tile;
    for (int t = blockIdx.x; t < ntiles; t += gridDim.x) {
        const long long base = (long long)t * tile + threadIdx.x;
        f32x4 lv[U], uv[U];
        // burst 1: 32 KiB contiguous from lo
        #pragma unroll
        for (int k = 0; k < U; ++k) lv[k] = nt_load(&lo[base + k * blockDim.x]);
        // burst 2: 32 KiB contiguous from up
        #pragma unroll
        for (int k = 0; k < U; ++k) uv[k] = nt_load(&up[base + k * blockDim.x]);

        f32x4 lo_o[U], up_o[U];
        #pragma unroll
        for (int k = 0; k < U; ++k) {
            #pragma unroll
            for (int j = 0; j < 4; ++j) {
                float a, b;
                bounds_one(lv[k][j], uv[k][j], a, b);
                lo_o[k][j] = a; up_o[k][j] = b;
            }
        }
        // burst stores per array
        #pragma unroll
        for (int k = 0; k < U; ++k) nt_store(&lo_out[base + k * blockDim.x], lo_o[k]);
        #pragma unroll
        for (int k = 0; k < U; ++k) nt_store(&up_out[base + k * blockDim.x], up_o[k]);
    }
    const int rem = ntiles * tile;
    for (int i = rem + blockIdx.x * blockDim.x + threadIdx.x; i < n4;
         i += gridDim.x * blockDim.x) {
        f32x4 lv = nt_load(&lo[i]);
        f32x4 uv = nt_load(&up[i]);
        f32x4 lo_o, up_o;
        #pragma unroll
        for (int j = 0; j < 4; ++j) {
            float a, b;
            bounds_one(lv[j], uv[j], a, b);
            lo_o[j] = a; up_o[j] = b;
        }
        nt_store(&lo_out[i], lo_o);
        nt_store(&up_out[i], up_o);
    }
}

// Scalar tail for N not divisible by 4 (not expected at N=16.7M).
__global__ void deeppoly_relu_tail(
    const float* __restrict__ x, const float* __restrict__ lo,
    const float* __restrict__ up, float* __restrict__ x_out,
    float* __restrict__ lo_out, float* __restrict__ up_out, int start, int n)
{
    int i = start + blockIdx.x * blockDim.x + threadIdx.x;
    if (i < n) {
        x_out[i] = fmaxf(x[i], 0.0f);
        float a, b;
        bounds_one(lo[i], up[i], a, b);
        lo_out[i] = a; up_out[i] = b;
    }
}

extern "C" void kernel_launch(void* const* d_in, const int* in_sizes, int n_in,
                              void* d_out, int out_size, void* d_ws, size_t ws_size,
                              hipStream_t stream) {
    const float* x  = (const float*)d_in[0];
    const float* lo = (const float*)d_in[1];
    const float* up = (const float*)d_in[2];
    float* out = (float*)d_out;

    const int n = in_sizes[0];
    float* x_out  = out;
    float* lo_out = out + (size_t)n;
    float* up_out = out + 2 * (size_t)n;

    const int n4 = n / 4;
    const int block = 256;
    const int tile = block * U;                  // 2048 float4 = 32 KiB
    const int ntiles = n4 / tile;                // 2048 at N=16.7M

    int grid = ntiles > 0 ? (ntiles < 2048 ? ntiles : 2048) : 1;

    relu_x_kernel<<<grid, block, 0, stream>>>(
        (const f32x4*)x, (f32x4*)x_out, n4);
    relu_bounds_kernel<<<grid, block, 0, stream>>>(
        (const f32x4*)lo, (const f32x4*)up, (f32x4*)lo_out, (f32x4*)up_out, n4);

    const int tail_start = n4 * 4;
    const int tail = n - tail_start;
    if (tail > 0) {
        deeppoly_relu_tail<<<(tail + 255) / 256, 256, 0, stream>>>(
            x, lo, up, x_out, lo_out, up_out, tail_start, n);
    }
}

// Round 6
// 71.110 us; speedup vs baseline: 1.0273x; 1.0273x over previous
//
#include <hip/hip_runtime.h>

// DeepPoly ReLU — HBM-bound streaming, 402.6 MB single-touch traffic.
// FINAL (revert to Round-4 winner, 71.0 µs ≈ 5.7 TB/s ≈ 90% of measured
// 6.29 TB/s mixed-R/W ceiling):
//  - Two kernels (stream-count split: 1R+1W relu-copy, then 2R+2W bounds).
//    6-stream fused version ran 4.94 TB/s; split runs 5.67 TB/s.
//  - Block-contiguous 32 KiB tiles per array, float4 lanes, nontemporal
//    (zero reuse, working set >> L3).
//  - Per-index interleaved lo/up access in kernel B (R5 showed per-array
//    burst reordering is neutral-to-worse).

#define U 8  // float4 per thread per tile

typedef float f32x4 __attribute__((ext_vector_type(4)));

__device__ __forceinline__ f32x4 nt_load(const f32x4* p) {
    return __builtin_nontemporal_load(p);
}
__device__ __forceinline__ void nt_store(f32x4* p, f32x4 v) {
    __builtin_nontemporal_store(v, p);
}

__device__ __forceinline__ void bounds_one(float lf, float uf,
                                           float& lo_o, float& up_o) {
    const bool neg = (uf <= 0.0f);          // fully inactive
    const bool pos = (lf >= 0.0f);          // fully active (after neg)
    const bool crossing = (!neg) && (!pos);
    const float denom = crossing ? (uf - lf) : 1.0f;  // >0 when crossing
    const float su = (uf / denom) * uf;     // slope*u, uniform (no divergence)
    lo_o = neg ? 0.0f : (pos ? uf : lf);
    up_o = neg ? 0.0f : (pos ? uf : su);
}

// ---- Kernel A: relu copy (1R + 1W) ----
__global__ void __launch_bounds__(256) relu_x_kernel(
    const f32x4* __restrict__ x, f32x4* __restrict__ x_out, int n4)
{
    const int tile = blockDim.x * U;             // 2048 float4 = 32 KiB
    const int ntiles = n4 / tile;
    for (int t = blockIdx.x; t < ntiles; t += gridDim.x) {
        const long long base = (long long)t * tile + threadIdx.x;
        f32x4 v[U];
        #pragma unroll
        for (int k = 0; k < U; ++k) v[k] = nt_load(&x[base + k * blockDim.x]);
        #pragma unroll
        for (int k = 0; k < U; ++k) {
            f32x4 r;
            r.x = fmaxf(v[k].x, 0.0f); r.y = fmaxf(v[k].y, 0.0f);
            r.z = fmaxf(v[k].z, 0.0f); r.w = fmaxf(v[k].w, 0.0f);
            nt_store(&x_out[base + k * blockDim.x], r);
        }
    }
    const int rem = ntiles * tile;
    for (int i = rem + blockIdx.x * blockDim.x + threadIdx.x; i < n4;
         i += gridDim.x * blockDim.x) {
        f32x4 v = nt_load(&x[i]);
        f32x4 r;
        r.x = fmaxf(v.x, 0.0f); r.y = fmaxf(v.y, 0.0f);
        r.z = fmaxf(v.z, 0.0f); r.w = fmaxf(v.w, 0.0f);
        nt_store(&x_out[i], r);
    }
}

// ---- Kernel B: bounds (2R + 2W), per-index interleave (R4 winner) ----
__global__ void __launch_bounds__(256) relu_bounds_kernel(
    const f32x4* __restrict__ lo, const f32x4* __restrict__ up,
    f32x4* __restrict__ lo_out, f32x4* __restrict__ up_out, int n4)
{
    const int tile = blockDim.x * U;
    const int ntiles = n4 / tile;
    for (int t = blockIdx.x; t < ntiles; t += gridDim.x) {
        const long long base = (long long)t * tile + threadIdx.x;
        f32x4 lv[U], uv[U];
        #pragma unroll
        for (int k = 0; k < U; ++k) {
            lv[k] = nt_load(&lo[base + k * blockDim.x]);
            uv[k] = nt_load(&up[base + k * blockDim.x]);
        }
        #pragma unroll
        for (int k = 0; k < U; ++k) {
            f32x4 lo_o, up_o;
            #pragma unroll
            for (int j = 0; j < 4; ++j) {
                float a, b;
                bounds_one(lv[k][j], uv[k][j], a, b);
                lo_o[j] = a; up_o[j] = b;
            }
            nt_store(&lo_out[base + k * blockDim.x], lo_o);
            nt_store(&up_out[base + k * blockDim.x], up_o);
        }
    }
    const int rem = ntiles * tile;
    for (int i = rem + blockIdx.x * blockDim.x + threadIdx.x; i < n4;
         i += gridDim.x * blockDim.x) {
        f32x4 lv = nt_load(&lo[i]);
        f32x4 uv = nt_load(&up[i]);
        f32x4 lo_o, up_o;
        #pragma unroll
        for (int j = 0; j < 4; ++j) {
            float a, b;
            bounds_one(lv[j], uv[j], a, b);
            lo_o[j] = a; up_o[j] = b;
        }
        nt_store(&lo_out[i], lo_o);
        nt_store(&up_out[i], up_o);
    }
}

// Scalar tail for N not divisible by 4 (not taken at N=16.7M).
__global__ void deeppoly_relu_tail(
    const float* __restrict__ x, const float* __restrict__ lo,
    const float* __restrict__ up, float* __restrict__ x_out,
    float* __restrict__ lo_out, float* __restrict__ up_out, int start, int n)
{
    int i = start + blockIdx.x * blockDim.x + threadIdx.x;
    if (i < n) {
        x_out[i] = fmaxf(x[i], 0.0f);
        float a, b;
        bounds_one(lo[i], up[i], a, b);
        lo_out[i] = a; up_out[i] = b;
    }
}

extern "C" void kernel_launch(void* const* d_in, const int* in_sizes, int n_in,
                              void* d_out, int out_size, void* d_ws, size_t ws_size,
                              hipStream_t stream) {
    const float* x  = (const float*)d_in[0];
    const float* lo = (const float*)d_in[1];
    const float* up = (const float*)d_in[2];
    float* out = (float*)d_out;

    const int n = in_sizes[0];
    float* x_out  = out;
    float* lo_out = out + (size_t)n;
    float* up_out = out + 2 * (size_t)n;

    const int n4 = n / 4;
    const int block = 256;
    const int tile = block * U;                  // 2048 float4 = 32 KiB
    const int ntiles = n4 / tile;                // 2048 at N=16.7M

    int grid = ntiles > 0 ? (ntiles < 2048 ? ntiles : 2048) : 1;

    relu_x_kernel<<<grid, block, 0, stream>>>(
        (const f32x4*)x, (f32x4*)x_out, n4);
    relu_bounds_kernel<<<grid, block, 0, stream>>>(
        (const f32x4*)lo, (const f32x4*)up, (f32x4*)lo_out, (f32x4*)up_out, n4);

    const int tail_start = n4 * 4;
    const int tail = n - tail_start;
    if (tail > 0) {
        deeppoly_relu_tail<<<(tail + 255) / 256, 256, 0, stream>>>(
            x, lo, up, x_out, lo_out, up_out, tail_start, n);
    }
}